// Round 5
// baseline (78.889 us; speedup 1.0000x reference)
//
#include <hip/hip_runtime.h>
#include <hip/hip_bf16.h>

typedef float f32x4 __attribute__((ext_vector_type(4)));
typedef __bf16 bf16x8 __attribute__((ext_vector_type(8)));

union Frag { unsigned short h[8]; unsigned int u[4]; uint4 u4; bf16x8 b; };

__device__ __forceinline__ unsigned short f2bs(float f){
  __hip_bfloat16 v = __float2bfloat16(f);
  return __builtin_bit_cast(unsigned short, v);
}
// 1-instruction bf16 pair pack (RNE)
__device__ __forceinline__ unsigned int pk2(float a, float b){
  unsigned int r;
  asm("v_cvt_pk_bf16_f32 %0, %1, %2" : "=v"(r) : "v"(a), "v"(b));
  return r;
}
__device__ __forceinline__ Frag packF(f32x4 a, f32x4 b){
  Frag f;
  f.u[0] = pk2(a[0], a[1]); f.u[1] = pk2(a[2], a[3]);
  f.u[2] = pk2(b[0], b[1]); f.u[3] = pk2(b[2], b[3]);
  return f;
}
__device__ __forceinline__ f32x4 relu4(f32x4 v){
  f32x4 r;
  #pragma unroll
  for (int j = 0; j < 4; ++j) r[j] = fmaxf(v[j], 0.f);
  return r;
}
__device__ __forceinline__ float sigmoid_fast(float x){
  return __builtin_amdgcn_rcpf(1.f + __expf(-x));
}

// ---------------------------------------------------------------------------
// Prep: weight matrices -> MFMA A-frag order bf16 (ws[0..4095] uint4), plus
// r2e's 5 rows pre-packed as B-frag pairs (ws[4096..4735]).
// A-frag element (h,j): W[16*m + (lane&15)][32*s + 16*h + 4*(lane>>4) + j]
// ---------------------------------------------------------------------------
__global__ void prep_weights(const float* __restrict__ w1, const float* __restrict__ w2,
                             const float* __restrict__ mu, const float* __restrict__ a1,
                             const float* __restrict__ a2, const float* __restrict__ r2e,
                             uint4* __restrict__ ws){
  const int f = blockIdx.x;
  const int l = threadIdx.x;
  Frag fr;
  if (f < 64){
    const float* W; int m, s, K;
    if (f < 16)      { W = w1; m = f >> 2;        s = f & 3;        K = 128; }
    else if (f < 24) { W = w2; m = (f - 16) >> 1; s = (f - 16) & 1; K = 64;  }
    else if (f < 40) { W = mu; m = (f - 24) >> 2; s = (f - 24) & 3; K = 128; }
    else if (f < 56) { W = a1; m = (f - 40) >> 2; s = (f - 40) & 3; K = 128; }
    else             { W = a2; m = (f - 56) >> 1; s = (f - 56) & 1; K = 64;  }
    const int row = 16 * m + (l & 15);
    const int k0  = 32 * s + 4 * (l >> 4);
    #pragma unroll
    for (int h = 0; h < 2; ++h)
      #pragma unroll
      for (int j = 0; j < 4; ++j)
        fr.h[4*h + j] = f2bs(W[row * K + k0 + 16*h + j]);
    ws[f * 64 + l] = fr.u4;
  } else {
    const int f2 = f - 64;            // 0..9
    const int R = f2 >> 1, sp = f2 & 1;
    const int g = (l >> 4) & 3;
    #pragma unroll
    for (int h = 0; h < 2; ++h)
      #pragma unroll
      for (int j = 0; j < 4; ++j)
        fr.h[4*h + j] = f2bs(r2e[R * 64 + sp * 32 + 16*h + 4*g + j]);
    ws[4096 + f2 * 64 + l] = fr.u4;
  }
}

// ---------------------------------------------------------------------------
// Main: ONE WAVE per block, one node per wave, grid = 2048.
// All 64 weight fragments live in the unified VGPR/AGPR file (256 regs,
// loaded once, only ever consumed as MFMA A-operands -> AGPR-resident, zero
// per-use moves, zero LDS weight reads). __launch_bounds__(64,1) grants the
// full 512-reg budget (round 3 taught us: never request MORE waves than the
// register need allows; here we request FEWER to unlock the budget).
// LDS holds only biases (1.5KB) + r2e B-frags (10KB).
// ---------------------------------------------------------------------------
__global__ __launch_bounds__(64, 1)
void uv_agg_main(const int* __restrict__ nodes, const int* __restrict__ huv,
                 const int* __restrict__ hr, const float* __restrict__ u2e,
                 const float* __restrict__ v2e,
                 const float* __restrict__ b1g, const float* __restrict__ b2g,
                 const float* __restrict__ bmg, const float* __restrict__ ba1g,
                 const float* __restrict__ ba2g, const float* __restrict__ a3g,
                 const uint4* __restrict__ wsfrag, float* __restrict__ out){
  __shared__ float bias[384];
  __shared__ uint4 rlds[640];

  const int lane = threadIdx.x;
  const int g    = lane >> 4;
  const int r16  = lane & 15;
  const int n    = blockIdx.x;

  // stage biases + r2e frags into LDS (single wave -> barrier is cheap)
  #pragma unroll
  for (int k = 0; k < 6; ++k){
    const int i = k * 64 + lane;
    const int w = i >> 6, d = i & 63;
    const float* src = (w==0)?b1g:(w==1)?b2g:(w==2)?bmg:(w==3)?ba1g:(w==4)?ba2g:a3g;
    bias[i] = src[d];
  }
  #pragma unroll
  for (int k = 0; k < 10; ++k)
    rlds[k * 64 + lane] = wsfrag[4096 + k * 64 + lane];

  // ALL weight frags -> registers (unified VGPR/AGPR file), used only as
  // MFMA A-operands. Static indexing everywhere below.
  Frag W[64];
  #pragma unroll
  for (int i = 0; i < 64; ++i) W[i].u4 = wsfrag[i * 64 + lane];

  __syncthreads();

  const f32x4* bl = (const f32x4*)bias + g;   // index st*16+4m -> const offset

  // per-node q = v2e[nodes[n]]
  const int item = nodes[n];
  f32x4 qv[4];
  #pragma unroll
  for (int m = 0; m < 4; ++m)
    qv[m] = *(const f32x4*)(v2e + (size_t)item * 64 + 16*m + 4*g);
  Frag qf[2];
  qf[0] = packF(qv[0], qv[1]); qf[1] = packF(qv[2], qv[3]);

  float sw = 0.f;
  f32x4 accw[4];
  #pragma unroll
  for (int m = 0; m < 4; ++m) accw[m] = (f32x4)(0.f);

  // prefetch tile 0 gather
  int iu = huv[n * 200 + r16];
  int ir = hr [n * 200 + r16];
  f32x4 ur[4];
  {
    const f32x4* urow = (const f32x4*)(u2e + (size_t)iu * 64);
    #pragma unroll
    for (int s = 0; s < 4; ++s) ur[s] = urow[4*s + g];
  }

  for (int t = 0; t < 13; ++t){
    const bool valid = (t * 16 + r16) < 200;

    Frag b0[2];
    b0[0] = packF(ur[0], ur[1]); b0[1] = packF(ur[2], ur[3]);
    const int irc = ir;

    // prefetch next tile (independent of this tile's chain)
    int iun = iu, irn = ir;
    f32x4 urn[4];
    #pragma unroll
    for (int s = 0; s < 4; ++s) urn[s] = ur[s];
    if (t < 12){
      const int rn = min(t * 16 + 16 + r16, 199);
      iun = huv[n * 200 + rn]; irn = hr[n * 200 + rn];
      const f32x4* urown = (const f32x4*)(u2e + (size_t)iun * 64);
      #pragma unroll
      for (int s = 0; s < 4; ++s) urn[s] = urown[4*s + g];
    }

    // S1: X = relu(W1 @ concat(e_uv, e_r) + b1)
    f32x4 X[4];
    #pragma unroll
    for (int m = 0; m < 4; ++m){
      f32x4 acc = bl[0*16 + 4*m];
      #pragma unroll
      for (int s = 0; s < 4; ++s){
        Frag bin;
        if (s < 2) bin = b0[s];
        else       bin.u4 = *(const uint4*)((const unsigned char*)rlds + (size_t)(irc*2 + (s-2))*1024 + lane*16);
        acc = __builtin_amdgcn_mfma_f32_16x16x32_bf16(W[m*4 + s].b, bin.b, acc, 0, 0, 0);
      }
      X[m] = relu4(acc);
    }
    Frag bx[2];
    bx[0] = packF(X[0], X[1]); bx[1] = packF(X[2], X[3]);

    // S2: O = relu(W2 @ X + b2)
    f32x4 O[4];
    #pragma unroll
    for (int m = 0; m < 4; ++m){
      f32x4 acc = bl[1*16 + 4*m];
      #pragma unroll
      for (int s = 0; s < 2; ++s)
        acc = __builtin_amdgcn_mfma_f32_16x16x32_bf16(W[16 + m*2 + s].b, bx[s].b, acc, 0, 0, 0);
      O[m] = relu4(acc);
    }
    Frag bo[2];
    bo[0] = packF(O[0], O[1]); bo[1] = packF(O[2], O[3]);

    // S3: gate = sigmoid(MU @ concat(O,q) + mu_b); OG = q + gate*(O-q)
    f32x4 OG[4];
    #pragma unroll
    for (int m = 0; m < 4; ++m){
      f32x4 acc = bl[2*16 + 4*m];
      #pragma unroll
      for (int s = 0; s < 4; ++s)
        acc = __builtin_amdgcn_mfma_f32_16x16x32_bf16(W[24 + m*4 + s].b,
                (s < 2) ? bo[s].b : qf[s-2].b, acc, 0, 0, 0);
      #pragma unroll
      for (int j = 0; j < 4; ++j){
        const float gg = sigmoid_fast(acc[j]);
        OG[m][j] = fmaf(gg, O[m][j] - qv[m][j], qv[m][j]);
      }
    }
    Frag bg[2];
    bg[0] = packF(OG[0], OG[1]); bg[1] = packF(OG[2], OG[3]);

    // S4: A1 = relu(ATT1 @ concat(OG,q) + att1_b)
    f32x4 A1[4];
    #pragma unroll
    for (int m = 0; m < 4; ++m){
      f32x4 acc = bl[3*16 + 4*m];
      #pragma unroll
      for (int s = 0; s < 4; ++s)
        acc = __builtin_amdgcn_mfma_f32_16x16x32_bf16(W[40 + m*4 + s].b,
                (s < 2) ? bg[s].b : qf[s-2].b, acc, 0, 0, 0);
      A1[m] = relu4(acc);
    }
    Frag b4[2];
    b4[0] = packF(A1[0], A1[1]); b4[1] = packF(A1[2], A1[3]);

    // S5: A2 = relu(ATT2 @ A1 + att2_b); logit = dot(att3_w, A2_row)
    float p = 0.f;
    #pragma unroll
    for (int m = 0; m < 4; ++m){
      f32x4 acc = bl[4*16 + 4*m];
      #pragma unroll
      for (int s = 0; s < 2; ++s)
        acc = __builtin_amdgcn_mfma_f32_16x16x32_bf16(W[56 + m*2 + s].b, b4[s].b, acc, 0, 0, 0);
      acc = relu4(acc);
      const f32x4 a3m = bl[5*16 + 4*m];
      #pragma unroll
      for (int j = 0; j < 4; ++j) p = fmaf(a3m[j], acc[j], p);
    }
    p += __shfl_xor(p, 16);
    p += __shfl_xor(p, 32);                 // full row logit, uniform over g

    // max-free online softmax (logits are O(1e-2); guard at 60)
    const float e = valid ? __expf(fminf(p, 60.f)) : 0.f;
    float es = e;
    #pragma unroll
    for (int o = 1; o < 16; o <<= 1) es += __shfl_xor(es, o);
    sw += es;
    #pragma unroll
    for (int m = 0; m < 4; ++m)
      #pragma unroll
      for (int j = 0; j < 4; ++j)
        accw[m][j] = fmaf(e, OG[m][j], accw[m][j]);

    iu = iun; ir = irn;
    #pragma unroll
    for (int s = 0; s < 4; ++s) ur[s] = urn[s];
  }

  // finale: reduce over the 16 row-lanes, scale, store
  #pragma unroll
  for (int m = 0; m < 4; ++m)
    #pragma unroll
    for (int j = 0; j < 4; ++j)
      #pragma unroll
      for (int o = 1; o < 16; o <<= 1)
        accw[m][j] += __shfl_xor(accw[m][j], o);
  if (r16 == 0){
    const float inv = 1.f / sw;
    #pragma unroll
    for (int m = 0; m < 4; ++m){
      f32x4 v = accw[m];
      #pragma unroll
      for (int j = 0; j < 4; ++j) v[j] *= inv;
      *(f32x4*)(out + (size_t)n * 64 + 16*m + 4*g) = v;
    }
  }
}

extern "C" void kernel_launch(void* const* d_in, const int* in_sizes, int n_in,
                              void* d_out, int out_size, void* d_ws, size_t ws_size,
                              hipStream_t stream){
  const int*   nodes = (const int*)  d_in[0];
  const int*   huv   = (const int*)  d_in[1];
  const int*   hr    = (const int*)  d_in[2];
  const float* u2e   = (const float*)d_in[3];
  const float* v2e   = (const float*)d_in[4];
  const float* r2e   = (const float*)d_in[5];
  const float* w1    = (const float*)d_in[6];
  const float* b1    = (const float*)d_in[7];
  const float* w2    = (const float*)d_in[8];
  const float* b2    = (const float*)d_in[9];
  const float* muw   = (const float*)d_in[10];
  const float* mub   = (const float*)d_in[11];
  const float* a1w   = (const float*)d_in[12];
  const float* a1b   = (const float*)d_in[13];
  const float* a2w   = (const float*)d_in[14];
  const float* a2b   = (const float*)d_in[15];
  const float* a3w   = (const float*)d_in[16];
  // d_in[17] = att3_b: constant logit offset -> cancels in softmax.

  const int N = in_sizes[0];            // 2048
  uint4* ws = (uint4*)d_ws;             // 74 KiB: frag table + r2e frags

  hipLaunchKernelGGL(prep_weights, dim3(74), dim3(64), 0, stream,
                     w1, w2, muw, a1w, a2w, r2e, ws);
  hipLaunchKernelGGL(uv_agg_main, dim3(N), dim3(64), 0, stream,
                     nodes, huv, hr, u2e, v2e,
                     b1, b2, mub, a1b, a2b, a3w,
                     (const uint4*)ws, (float*)d_out);
}

// Round 6
// 53.645 us; speedup vs baseline: 1.4706x; 1.4706x over previous
//
#include <hip/hip_runtime.h>
#include <hip/hip_bf16.h>

typedef float f32x4 __attribute__((ext_vector_type(4)));
typedef __bf16 bf16x8 __attribute__((ext_vector_type(8)));

union Frag { unsigned short h[8]; unsigned int u[4]; uint4 u4; bf16x8 b; };

__device__ __forceinline__ unsigned short f2bs(float f){
  __hip_bfloat16 v = __float2bfloat16(f);
  return __builtin_bit_cast(unsigned short, v);
}
// 1-instruction bf16 pair pack (RNE)
__device__ __forceinline__ unsigned int pk2(float a, float b){
  unsigned int r;
  asm("v_cvt_pk_bf16_f32 %0, %1, %2" : "=v"(r) : "v"(a), "v"(b));
  return r;
}
__device__ __forceinline__ Frag packF(f32x4 a, f32x4 b){
  Frag f;
  f.u[0] = pk2(a[0], a[1]); f.u[1] = pk2(a[2], a[3]);
  f.u[2] = pk2(b[0], b[1]); f.u[3] = pk2(b[2], b[3]);
  return f;
}
__device__ __forceinline__ f32x4 relu4(f32x4 v){
  f32x4 r;
  #pragma unroll
  for (int j = 0; j < 4; ++j) r[j] = fmaxf(v[j], 0.f);
  return r;
}
__device__ __forceinline__ float sigmoid_fast(float x){
  return __builtin_amdgcn_rcpf(1.f + __expf(-x));
}

// ---------------------------------------------------------------------------
// Prep: weight matrices -> MFMA A-frag order bf16 (ws[0..4095] uint4), plus
// r2e's 5 rows pre-packed as B-frag pairs (ws[4096..4735]).
// A-frag element (h,j): W[16*m + (lane&15)][32*s + 16*h + 4*(lane>>4) + j]
// ---------------------------------------------------------------------------
__global__ void prep_weights(const float* __restrict__ w1, const float* __restrict__ w2,
                             const float* __restrict__ mu, const float* __restrict__ a1,
                             const float* __restrict__ a2, const float* __restrict__ r2e,
                             uint4* __restrict__ ws){
  const int f = blockIdx.x;
  const int l = threadIdx.x;
  Frag fr;
  if (f < 64){
    const float* W; int m, s, K;
    if (f < 16)      { W = w1; m = f >> 2;        s = f & 3;        K = 128; }
    else if (f < 24) { W = w2; m = (f - 16) >> 1; s = (f - 16) & 1; K = 64;  }
    else if (f < 40) { W = mu; m = (f - 24) >> 2; s = (f - 24) & 3; K = 128; }
    else if (f < 56) { W = a1; m = (f - 40) >> 2; s = (f - 40) & 3; K = 128; }
    else             { W = a2; m = (f - 56) >> 1; s = (f - 56) & 1; K = 64;  }
    const int row = 16 * m + (l & 15);
    const int k0  = 32 * s + 4 * (l >> 4);
    #pragma unroll
    for (int h = 0; h < 2; ++h)
      #pragma unroll
      for (int j = 0; j < 4; ++j)
        fr.h[4*h + j] = f2bs(W[row * K + k0 + 16*h + j]);
    ws[f * 64 + l] = fr.u4;
  } else {
    const int f2 = f - 64;            // 0..9
    const int R = f2 >> 1, sp = f2 & 1;
    const int g = (l >> 4) & 3;
    #pragma unroll
    for (int h = 0; h < 2; ++h)
      #pragma unroll
      for (int j = 0; j < 4; ++j)
        fr.h[4*h + j] = f2bs(r2e[R * 64 + sp * 32 + 16*h + 4*g + j]);
    ws[4096 + f2 * 64 + l] = fr.u4;
  }
}

// ---------------------------------------------------------------------------
// Main: grid 512 x 256thr, wave w owns node n = b*4+w. DUAL-CHUNK: each
// iteration processes TWO 16-row tiles (2it, 2it+1) as independent chains
// interleaved at each stage -> 2x ILP on the dependent MFMA/VALU chain, and
// each weight/bias LDS read is reused by both chunks. 7 iterations cover 14
// tiles (tile 13 = fully masked, tile 12 = rows 192..199 valid).
// NOTE: no min-waves launch_bounds arg (round 3: cap => ~1GB scratch spill).
// LDS (77312 B): [0,65536) uint4 wlds[4096]; [65536,67072) float bias[384];
//                [67072,77312) uint4 rlds[640]
// ---------------------------------------------------------------------------
__global__ __launch_bounds__(256)
void uv_agg_main(const int* __restrict__ nodes, const int* __restrict__ huv,
                 const int* __restrict__ hr, const float* __restrict__ u2e,
                 const float* __restrict__ v2e,
                 const float* __restrict__ b1g, const float* __restrict__ b2g,
                 const float* __restrict__ bmg, const float* __restrict__ ba1g,
                 const float* __restrict__ ba2g, const float* __restrict__ a3g,
                 const uint4* __restrict__ wsfrag, float* __restrict__ out){
  extern __shared__ unsigned char smem[];
  uint4* wlds = (uint4*)smem;
  float* bias = (float*)(smem + 65536);
  uint4* rlds = (uint4*)(smem + 67072);

  const int tid  = threadIdx.x;
  const int lane = tid & 63;
  const int wave = tid >> 6;
  const int g    = lane >> 4;
  const int r16  = lane & 15;
  const int n    = blockIdx.x * 4 + wave;

  // stage weight frag table + r2e frags + biases into LDS
  #pragma unroll 4
  for (int i = tid; i < 4096; i += 256) wlds[i] = wsfrag[i];
  for (int i = tid; i < 640; i += 256)  rlds[i] = wsfrag[4096 + i];
  for (int i = tid; i < 384; i += 256){
    const int w = i >> 6, d = i & 63;
    const float* src = (w==0)?b1g:(w==1)?b2g:(w==2)?bmg:(w==3)?ba1g:(w==4)?ba2g:a3g;
    bias[i] = src[d];
  }
  __syncthreads();

  const uint4* wl = wlds + lane;
  const f32x4* bl = (const f32x4*)bias + g;
  const unsigned char* rbase = (const unsigned char*)rlds + lane * 16;
  const int* hu = huv + n * 200;
  const int* hrw = hr + n * 200;

  // per-node q = v2e[nodes[n]]
  const int item = nodes[n];
  f32x4 qv[4];
  #pragma unroll
  for (int m = 0; m < 4; ++m)
    qv[m] = *(const f32x4*)(v2e + (size_t)item * 64 + 16*m + 4*g);
  Frag qf[2];
  qf[0] = packF(qv[0], qv[1]); qf[1] = packF(qv[2], qv[3]);

  float sw = 0.f;
  f32x4 accw[4];
  #pragma unroll
  for (int m = 0; m < 4; ++m) accw[m] = (f32x4)(0.f);

  // initial gather: tiles 0 and 1
  int irA, irB;
  f32x4 urA[4], urB[4];
  {
    const int iuA = hu[r16];      irA = hrw[r16];
    const int iuB = hu[16 + r16]; irB = hrw[16 + r16];
    const f32x4* ua = (const f32x4*)(u2e + (size_t)iuA * 64);
    const f32x4* ub = (const f32x4*)(u2e + (size_t)iuB * 64);
    #pragma unroll
    for (int s = 0; s < 4; ++s){ urA[s] = ua[4*s + g]; urB[s] = ub[4*s + g]; }
  }

  for (int it = 0; it < 7; ++it){
    // pack current inputs, save r2e ids
    Frag b0A[2], b0B[2];
    b0A[0] = packF(urA[0], urA[1]); b0A[1] = packF(urA[2], urA[3]);
    b0B[0] = packF(urB[0], urB[1]); b0B[1] = packF(urB[2], urB[3]);
    const int ircA = irA, ircB = irB;
    const bool vA = (it < 6) || (r16 < 8);   // tile 12: rows 192..199
    const bool vB = (it < 6);                // tile 13: none

    // prefetch next pair (independent of this iteration's chains)
    if (it < 6){
      const int base = (2*it + 2) * 16;
      const int kA = min(base + r16, 199);
      const int kB = min(base + 16 + r16, 199);
      const int iuA = hu[kA]; irA = hrw[kA];
      const int iuB = hu[kB]; irB = hrw[kB];
      const f32x4* ua = (const f32x4*)(u2e + (size_t)iuA * 64);
      const f32x4* ub = (const f32x4*)(u2e + (size_t)iuB * 64);
      #pragma unroll
      for (int s = 0; s < 4; ++s){ urA[s] = ua[4*s + g]; urB[s] = ub[4*s + g]; }
    }

    // S1: X = relu(W1 @ concat(e_uv, e_r) + b1)   [two chunks interleaved]
    f32x4 XA[4], XB[4];
    #pragma unroll
    for (int m = 0; m < 4; ++m){
      const f32x4 bi = bl[0*16 + 4*m];
      f32x4 aA = bi, aB = bi;
      #pragma unroll
      for (int s = 0; s < 4; ++s){
        Frag w; w.u4 = wl[(m*4 + s) * 64];
        Frag eA, eB;
        if (s < 2){ eA = b0A[s]; eB = b0B[s]; }
        else {
          eA.u4 = *(const uint4*)(rbase + (size_t)(ircA*2 + (s-2)) * 1024);
          eB.u4 = *(const uint4*)(rbase + (size_t)(ircB*2 + (s-2)) * 1024);
        }
        aA = __builtin_amdgcn_mfma_f32_16x16x32_bf16(w.b, eA.b, aA, 0, 0, 0);
        aB = __builtin_amdgcn_mfma_f32_16x16x32_bf16(w.b, eB.b, aB, 0, 0, 0);
      }
      XA[m] = relu4(aA); XB[m] = relu4(aB);
    }
    Frag bxA[2], bxB[2];
    bxA[0] = packF(XA[0], XA[1]); bxA[1] = packF(XA[2], XA[3]);
    bxB[0] = packF(XB[0], XB[1]); bxB[1] = packF(XB[2], XB[3]);

    // S2: O = relu(W2 @ X + b2)
    f32x4 OA[4], OB[4];
    #pragma unroll
    for (int m = 0; m < 4; ++m){
      const f32x4 bi = bl[1*16 + 4*m];
      f32x4 aA = bi, aB = bi;
      #pragma unroll
      for (int s = 0; s < 2; ++s){
        Frag w; w.u4 = wl[(16 + m*2 + s) * 64];
        aA = __builtin_amdgcn_mfma_f32_16x16x32_bf16(w.b, bxA[s].b, aA, 0, 0, 0);
        aB = __builtin_amdgcn_mfma_f32_16x16x32_bf16(w.b, bxB[s].b, aB, 0, 0, 0);
      }
      OA[m] = relu4(aA); OB[m] = relu4(aB);
    }
    Frag boA[2], boB[2];
    boA[0] = packF(OA[0], OA[1]); boA[1] = packF(OA[2], OA[3]);
    boB[0] = packF(OB[0], OB[1]); boB[1] = packF(OB[2], OB[3]);

    // S3: gate = sigmoid(MU @ concat(O,q) + mu_b); OG = q + gate*(O-q)
    f32x4 OGA[4], OGB[4];
    #pragma unroll
    for (int m = 0; m < 4; ++m){
      const f32x4 bi = bl[2*16 + 4*m];
      f32x4 aA = bi, aB = bi;
      #pragma unroll
      for (int s = 0; s < 4; ++s){
        Frag w; w.u4 = wl[(24 + m*4 + s) * 64];
        const bf16x8 eA = (s < 2) ? boA[s].b : qf[s-2].b;
        const bf16x8 eB = (s < 2) ? boB[s].b : qf[s-2].b;
        aA = __builtin_amdgcn_mfma_f32_16x16x32_bf16(w.b, eA, aA, 0, 0, 0);
        aB = __builtin_amdgcn_mfma_f32_16x16x32_bf16(w.b, eB, aB, 0, 0, 0);
      }
      #pragma unroll
      for (int j = 0; j < 4; ++j){
        const float gA = sigmoid_fast(aA[j]);
        const float gB = sigmoid_fast(aB[j]);
        OGA[m][j] = fmaf(gA, OA[m][j] - qv[m][j], qv[m][j]);
        OGB[m][j] = fmaf(gB, OB[m][j] - qv[m][j], qv[m][j]);
      }
    }
    Frag bgA[2], bgB[2];
    bgA[0] = packF(OGA[0], OGA[1]); bgA[1] = packF(OGA[2], OGA[3]);
    bgB[0] = packF(OGB[0], OGB[1]); bgB[1] = packF(OGB[2], OGB[3]);

    // S4: A1 = relu(ATT1 @ concat(OG,q) + att1_b)
    f32x4 A1A[4], A1B[4];
    #pragma unroll
    for (int m = 0; m < 4; ++m){
      const f32x4 bi = bl[3*16 + 4*m];
      f32x4 aA = bi, aB = bi;
      #pragma unroll
      for (int s = 0; s < 4; ++s){
        Frag w; w.u4 = wl[(40 + m*4 + s) * 64];
        const bf16x8 eA = (s < 2) ? bgA[s].b : qf[s-2].b;
        const bf16x8 eB = (s < 2) ? bgB[s].b : qf[s-2].b;
        aA = __builtin_amdgcn_mfma_f32_16x16x32_bf16(w.b, eA, aA, 0, 0, 0);
        aB = __builtin_amdgcn_mfma_f32_16x16x32_bf16(w.b, eB, aB, 0, 0, 0);
      }
      A1A[m] = relu4(aA); A1B[m] = relu4(aB);
    }
    Frag b4A[2], b4B[2];
    b4A[0] = packF(A1A[0], A1A[1]); b4A[1] = packF(A1A[2], A1A[3]);
    b4B[0] = packF(A1B[0], A1B[1]); b4B[1] = packF(A1B[2], A1B[3]);

    // S5: A2 = relu(ATT2 @ A1 + att2_b); logit = dot(att3_w, A2_row)
    float pA = 0.f, pB = 0.f;
    #pragma unroll
    for (int m = 0; m < 4; ++m){
      const f32x4 bi = bl[4*16 + 4*m];
      f32x4 aA = bi, aB = bi;
      #pragma unroll
      for (int s = 0; s < 2; ++s){
        Frag w; w.u4 = wl[(56 + m*2 + s) * 64];
        aA = __builtin_amdgcn_mfma_f32_16x16x32_bf16(w.b, b4A[s].b, aA, 0, 0, 0);
        aB = __builtin_amdgcn_mfma_f32_16x16x32_bf16(w.b, b4B[s].b, aB, 0, 0, 0);
      }
      aA = relu4(aA); aB = relu4(aB);
      const f32x4 a3m = bl[5*16 + 4*m];
      #pragma unroll
      for (int j = 0; j < 4; ++j){
        pA = fmaf(a3m[j], aA[j], pA);
        pB = fmaf(a3m[j], aB[j], pB);
      }
    }
    pA += __shfl_xor(pA, 16); pA += __shfl_xor(pA, 32);
    pB += __shfl_xor(pB, 16); pB += __shfl_xor(pB, 32);

    // max-free online softmax (logits O(1e-2); guard at 60)
    const float eA = vA ? __expf(fminf(pA, 60.f)) : 0.f;
    const float eB = vB ? __expf(fminf(pB, 60.f)) : 0.f;
    float esA = eA, esB = eB;
    #pragma unroll
    for (int o = 1; o < 16; o <<= 1){
      esA += __shfl_xor(esA, o);
      esB += __shfl_xor(esB, o);
    }
    sw += esA + esB;
    #pragma unroll
    for (int m = 0; m < 4; ++m)
      #pragma unroll
      for (int j = 0; j < 4; ++j)
        accw[m][j] = fmaf(eA, OGA[m][j], fmaf(eB, OGB[m][j], accw[m][j]));
  }

  // finale: reduce over the 16 row-lanes, scale, store
  #pragma unroll
  for (int m = 0; m < 4; ++m)
    #pragma unroll
    for (int j = 0; j < 4; ++j)
      #pragma unroll
      for (int o = 1; o < 16; o <<= 1)
        accw[m][j] += __shfl_xor(accw[m][j], o);
  if (r16 == 0){
    const float inv = 1.f / sw;
    #pragma unroll
    for (int m = 0; m < 4; ++m){
      f32x4 v = accw[m];
      #pragma unroll
      for (int j = 0; j < 4; ++j) v[j] *= inv;
      *(f32x4*)(out + (size_t)n * 64 + 16*m + 4*g) = v;
    }
  }
}

extern "C" void kernel_launch(void* const* d_in, const int* in_sizes, int n_in,
                              void* d_out, int out_size, void* d_ws, size_t ws_size,
                              hipStream_t stream){
  const int*   nodes = (const int*)  d_in[0];
  const int*   huv   = (const int*)  d_in[1];
  const int*   hr    = (const int*)  d_in[2];
  const float* u2e   = (const float*)d_in[3];
  const float* v2e   = (const float*)d_in[4];
  const float* r2e   = (const float*)d_in[5];
  const float* w1    = (const float*)d_in[6];
  const float* b1    = (const float*)d_in[7];
  const float* w2    = (const float*)d_in[8];
  const float* b2    = (const float*)d_in[9];
  const float* muw   = (const float*)d_in[10];
  const float* mub   = (const float*)d_in[11];
  const float* a1w   = (const float*)d_in[12];
  const float* a1b   = (const float*)d_in[13];
  const float* a2w   = (const float*)d_in[14];
  const float* a2b   = (const float*)d_in[15];
  const float* a3w   = (const float*)d_in[16];
  // d_in[17] = att3_b: constant logit offset -> cancels in softmax.

  const int N = in_sizes[0];            // 2048
  uint4* ws = (uint4*)d_ws;             // 74 KiB: frag table + r2e frags

  hipLaunchKernelGGL(prep_weights, dim3(74), dim3(64), 0, stream,
                     w1, w2, muw, a1w, a2w, r2e, ws);
  hipLaunchKernelGGL(uv_agg_main, dim3(N / 4), dim3(256), 77312, stream,
                     nodes, huv, hr, u2e, v2e,
                     b1, b2, mub, a1b, a2b, a3w,
                     (const uint4*)ws, (float*)d_out);
}